// Round 12
// baseline (1029.779 us; speedup 1.0000x reference)
//
#include <hip/hip_runtime.h>
#include <hip/hip_fp16.h>
#include <math.h>

// Problem dims
#define TT 256
#define BB 64
#define DD 512
#define HH 512
#define NC 2048  // 4 gates * H, col = j*4+g (g: 0=i,1=f,2=o,3=ctilde)

// Workspace layout (float-slot offsets).
#define AH_OFF   0ull          // f16 [16384][1024]  (xt | m), row = t*64+b
#define DLH_OFF  8388608ull    // f16 [16384][512]   Dl
#define DH_OFF   12582912ull   // f32 [16384][512]   delta_h
#define GP_OFF   20971520ull   // f16 [16384][2048]  G_pre
#define WCT_OFF  37748736ull   // f16 [2048][1024]   gate W (x|m), col-major rows
#define GHT_OFF  38797312ull   // f16 [512][512]     gh_W transposed
#define WHT_OFF  38928384ull   // f16 [2048][512]    gate W h-part, col-major rows
#define BC_OFF   39452672ull   // f32 [2048]
#define HS_OFF   39454720ull   // uint [2][4 groups][4096] frag-linear h exchange
#define FLG_OFF  39487488ull   // int [64] flags + int [256] producer counters

typedef _Float16 h8_t __attribute__((ext_vector_type(8)));
typedef _Float16 h4_t __attribute__((ext_vector_type(4)));
typedef float f32x4 __attribute__((ext_vector_type(4)));
typedef unsigned long long ull2_t __attribute__((ext_vector_type(2)));

typedef const __attribute__((address_space(1))) void* gas_p;
typedef __attribute__((address_space(3))) void* las_p;

__device__ __forceinline__ float fast_exp2(float x) {
#if defined(__has_builtin)
#if __has_builtin(__builtin_amdgcn_exp2f)
  return __builtin_amdgcn_exp2f(x);
#else
  return exp2f(x);
#endif
#else
  return exp2f(x);
#endif
}
__device__ __forceinline__ float fast_rcp(float x) {
#if defined(__has_builtin)
#if __has_builtin(__builtin_amdgcn_rcpf)
  return __builtin_amdgcn_rcpf(x);
#else
  return 1.0f / x;
#endif
#else
  return 1.0f / x;
#endif
}
#define LOG2E 1.4426950408889634f
__device__ __forceinline__ float sigmoidf_(float v) {
  return fast_rcp(1.0f + fast_exp2(-LOG2E * v));
}
__device__ __forceinline__ float tanhf_(float v) {
  return 1.0f - 2.0f * fast_rcp(1.0f + fast_exp2(2.0f * LOG2E * v));
}

// ---------------------------------------------------------------------------
// PREP kernel: xt (blocks 0..8191) + repack transpose (8192..9024) +
// HS/FLG/CNT zeroing (9025). Proven round-10/11 bodies; zero block extended
// to cover the 256 producer counters.
// ---------------------------------------------------------------------------
__global__ __launch_bounds__(256) void prep_kernel(
    const float* __restrict__ x, const float* __restrict__ Xmean,
    const float* __restrict__ gxw, const float* __restrict__ gxb,
    __half* __restrict__ AH, __half* __restrict__ DLh,
    const float* __restrict__ Wi, const float* __restrict__ bi,
    const float* __restrict__ Wf, const float* __restrict__ bff,
    const float* __restrict__ Wo, const float* __restrict__ bo,
    const float* __restrict__ Wc, const float* __restrict__ bc,
    const float* __restrict__ ghW,
    __half* __restrict__ WCT, __half* __restrict__ WHT,
    __half* __restrict__ GHT, float* __restrict__ BC,
    unsigned* __restrict__ HS) {
  const int bx = blockIdx.x;
  const int tid = threadIdx.x;

  if (bx < 8192) {
    // ---- xt: AH[r][d]=xt, AH[r][512+d]=m, DLh[r][d]=dl ; r=t*64+b ----
    int idx = bx * 256 + tid;
    int d = (idx & 127) * 4;
    int r = idx >> 7;
    int b = r & 63, t = r >> 6;
    size_t base = (((size_t)b * 4) * TT + t) * DD + d;
    const float4 X = *(const float4*)&x[base];
    const float4 Xl = *(const float4*)&x[base + (size_t)TT * DD];
    const float4 M = *(const float4*)&x[base + 2ull * TT * DD];
    const float4 Dl = *(const float4*)&x[base + 3ull * TT * DD];
    const float4 xm = *(const float4*)&Xmean[(size_t)t * DD + d];
    const float4 gw = *(const float4*)&gxw[d];
    const float4 gb = *(const float4*)&gxb[d];
    float o[4];
    {
      float dx = fast_exp2(-LOG2E * fmaxf(0.f, Dl.x * gw.x + gb.x));
      o[0] = M.x * X.x + (1.f - M.x) * (dx * Xl.x + (1.f - dx) * xm.x);
    }
    {
      float dx = fast_exp2(-LOG2E * fmaxf(0.f, Dl.y * gw.y + gb.y));
      o[1] = M.y * X.y + (1.f - M.y) * (dx * Xl.y + (1.f - dx) * xm.y);
    }
    {
      float dx = fast_exp2(-LOG2E * fmaxf(0.f, Dl.z * gw.z + gb.z));
      o[2] = M.z * X.z + (1.f - M.z) * (dx * Xl.z + (1.f - dx) * xm.z);
    }
    {
      float dx = fast_exp2(-LOG2E * fmaxf(0.f, Dl.w * gw.w + gb.w));
      o[3] = M.w * X.w + (1.f - M.w) * (dx * Xl.w + (1.f - dx) * xm.w);
    }
    h4_t xo = {(_Float16)o[0], (_Float16)o[1], (_Float16)o[2], (_Float16)o[3]};
    h4_t mo = {(_Float16)M.x, (_Float16)M.y, (_Float16)M.z, (_Float16)M.w};
    h4_t dlo = {(_Float16)Dl.x, (_Float16)Dl.y, (_Float16)Dl.z, (_Float16)Dl.w};
    *(h4_t*)&AH[(size_t)r * 1024 + d] = xo;
    *(h4_t*)&AH[(size_t)r * 1024 + 512 + d] = mo;
    *(h4_t*)&DLh[(size_t)r * 512 + d] = dlo;
    return;
  }

  if (bx == 9025) {  // zero HS (32768) + FLG (64) + CNT (256), contiguous
    for (int i = tid; i < 33088; i += 256) HS[i] = 0u;
    return;
  }

  const int rbx = bx - 8192;  // 0..832 repack
  if (rbx == 832) {           // bias block
    const float* bs[4] = {bi, bff, bo, bc};
    for (int j = tid; j < 512; j += 256)
#pragma unroll
      for (int g = 0; g < 4; ++g) BC[j * 4 + g] = bs[g][j];
    return;
  }
  __shared__ _Float16 tl[64][68];  // [jj][kk]; 136B rows: 8B-aligned, 2-way banks
  const int p = rbx % 13;          // panel
  const int tile = rbx / 13;       // 0..63
  const int k0 = (tile >> 3) << 6, j0 = (tile & 7) << 6;
  const float* Ws[4] = {Wi, Wf, Wo, Wc};

  const float* src;
  size_t koff;        // source row offset within W
  __half* dst;
  int dstride, dkoff, g = 0;
  if (p < 12) {
    g = p & 3;
    const int part = p >> 2;  // 0=x, 1=m, 2=h
    src = Ws[g];
    koff = (part == 0) ? 0 : (part == 1 ? 1024 : 512);
    if (part == 2) { dst = WHT; dstride = 512; dkoff = 0; }
    else           { dst = WCT; dstride = 1024; dkoff = (part == 1) ? 512 : 0; }
  } else {
    src = ghW; koff = 0; dst = GHT; dstride = 512; dkoff = 0;
  }

  // load 64x64 tile: lane -> jj (coalesced), 4 kk rows per pass
  const int jj = tid & 63, kr = tid >> 6;
#pragma unroll
  for (int r = 0; r < 16; ++r) {
    const int kk = r * 4 + kr;
    tl[jj][kk] = (_Float16)src[(koff + k0 + kk) * 512 + (j0 + jj)];
  }
  __syncthreads();

  // write transposed: thread -> (jj2, c4); h4 along k, 16 lanes = 128B run
  const int c4 = (tid & 15) * 4;
#pragma unroll
  for (int pass = 0; pass < 4; ++pass) {
    const int jj2 = (tid >> 4) + pass * 16;
    const h4_t v = *(const h4_t*)&tl[jj2][c4];
    size_t idx;
    if (p < 12)
      idx = (size_t)(4 * (j0 + jj2) + g) * dstride + dkoff + k0 + c4;
    else
      idx = (size_t)(j0 + jj2) * 512 + k0 + c4;
    *(h4_t*)&dst[idx] = v;
  }
}

// ---------------------------------------------------------------------------
// Producer tile: 512-thread 128x128 m97-structure GEMM tile (8 waves, each a
// 64x32 sub-tile: acc[4][2]). Same K-accumulation order as the proven 256-thr
// version -> identical numerics. Epilogue uses AGENT-scope relaxed atomic
// stores (cross-XCD visibility within the fused kernel, same pattern as the
// proven h-exchange), then per-wave vmcnt(0) drain + agent atomicAdd on the
// panel counter — count full == all 8 waves' stores of all tiles visible.
// ---------------------------------------------------------------------------
__device__ __forceinline__ void gemm_tile(
    _Float16* Ash, _Float16* Bsh,
    const __half* __restrict__ A, const __half* __restrict__ BT,
    const float* __restrict__ bias, void* __restrict__ C,
    int K, int Ncols, int mode, int row0, int col0, int* cntp) {
  const int tid = threadIdx.x;
  const int lane = tid & 63, w = tid >> 6;
  const int l15 = lane & 15, quad = lane >> 4;
  const int wr = w >> 2, wc = w & 3;

  f32x4 acc[4][2] = {};

  // staging: 512 chunks of 16B per operand; chunk tid = row tid>>2, cols (tid&3)*8
  const int ar = tid >> 2, ac = (tid & 3) * 8;
  const __half* Abase = A + (size_t)row0 * K;
  const __half* Bbase = BT + (size_t)col0 * K;

  for (int k0 = 0; k0 < K; k0 += 32) {
    __syncthreads();  // previous tile-step readers done
    __builtin_amdgcn_global_load_lds((gas_p)(Abase + (size_t)ar * K + k0 + ac),
                                     (las_p)(Ash + tid * 8), 16, 0, 0);
    __builtin_amdgcn_global_load_lds((gas_p)(Bbase + (size_t)ar * K + k0 + ac),
                                     (las_p)(Bsh + tid * 8), 16, 0, 0);
    __syncthreads();  // vmcnt(0) drain -> tiles resident
    h8_t af[4], bf[2];
#pragma unroll
    for (int mt = 0; mt < 4; ++mt)
      af[mt] = *(const h8_t*)&Ash[(wr * 64 + mt * 16 + l15) * 32 + quad * 8];
#pragma unroll
    for (int ct = 0; ct < 2; ++ct)
      bf[ct] = *(const h8_t*)&Bsh[(wc * 32 + ct * 16 + l15) * 32 + quad * 8];
#pragma unroll
    for (int mt = 0; mt < 4; ++mt)
#pragma unroll
      for (int ct = 0; ct < 2; ++ct)
        acc[mt][ct] = __builtin_amdgcn_mfma_f32_16x16x32_f16(af[mt], bf[ct], acc[mt][ct], 0, 0, 0);
  }

#pragma unroll
  for (int ct = 0; ct < 2; ++ct) {
    const int col = col0 + wc * 32 + ct * 16 + l15;
    const float bv = bias[col];
#pragma unroll
    for (int mt = 0; mt < 4; ++mt) {
#pragma unroll
      for (int reg = 0; reg < 4; ++reg) {
        const int row = row0 + wr * 64 + mt * 16 + quad * 4 + reg;
        float v = acc[mt][ct][reg] + bv;
        if (mode == 0) {
          __hip_atomic_store((unsigned short*)C + (size_t)row * Ncols + col,
                             (unsigned short)__half_as_ushort(__float2half(v)),
                             __ATOMIC_RELAXED, __HIP_MEMORY_SCOPE_AGENT);
        } else {
          __hip_atomic_store((float*)C + (size_t)row * Ncols + col,
                             fast_exp2(-LOG2E * fmaxf(0.f, v)),
                             __ATOMIC_RELAXED, __HIP_MEMORY_SCOPE_AGENT);
        }
      }
    }
  }
  // publish: this wave's stores drained, then count (panel full == all visible)
  asm volatile("s_waitcnt vmcnt(0)" ::: "memory");
  if (lane == 0)
    __hip_atomic_fetch_add(cntp, 1, __ATOMIC_RELAXED, __HIP_MEMORY_SCOPE_AGENT);
}

// ---------------------------------------------------------------------------
// FUSED cooperative kernel: 256 blocks x 512 threads, 1 block/CU.
//  Blocks 0..31 : persist recurrence, round-6 bytes (hardware-proven 639us),
//                 plus: poll gains GP/DH panel-counter checks; GPh/DH reads
//                 become agent atomic loads issued after the poll.
//  Blocks 32..255: producers. 2560 tiles (128 panels x [4 DH + 16 GP]) in
//                 ascending-t order, grid-stride 224. Producer rate ~7x the
//                 consumer rate -> persist waits only at startup.
// Panel p of GP ready when cnt[p]==128 (16 tiles x 8 waves); DH panel p ready
// when cnt[128+p]==32 (4 tiles x 8 waves). Step t needs GP panel t>>1 and DH
// panel (min(t+1,255))>>1. Producers never wait on persist -> no deadlock.
// ---------------------------------------------------------------------------
__global__ __launch_bounds__(512)
__attribute__((amdgpu_waves_per_eu(2, 2))) void fused_kernel(
    __half* __restrict__ GPh, float* __restrict__ DHf,
    const __half* __restrict__ WHT, unsigned* __restrict__ hs,
    int* __restrict__ flg, float* __restrict__ out,
    const __half* __restrict__ AH, const __half* __restrict__ WCT,
    const float* __restrict__ BC, const __half* __restrict__ DLh,
    const __half* __restrict__ GHT, const float* __restrict__ ghb) {
  __shared__ __align__(16) float gbuf[16 * 260];
  __shared__ __align__(16) unsigned long long stag[2048];  // 16KB A-slot mirror
  __shared__ _Float16 Ash[128 * 32];
  __shared__ _Float16 Bsh[128 * 32];
  int* cnt = flg + 64;  // [128] GP panel counters, [128] DH panel counters

  if (blockIdx.x >= 32) {
    // ================= PRODUCER =================
    const int pp = blockIdx.x - 32;  // 0..223
    for (int tau = pp; tau < 2560; tau += 224) {
      const int p = tau / 20, i = tau % 20;
      if (i < 4)
        gemm_tile(Ash, Bsh, DLh, GHT, ghb, (void*)DHf, 512, 512, 1,
                  p * 128, i * 128, &cnt[128 + p]);
      else
        gemm_tile(Ash, Bsh, AH, WCT, BC, (void*)GPh, 1024, NC, 0,
                  p * 128, (i - 4) * 128, &cnt[p]);
    }
    return;
  }

  // ================= PERSIST (round-6 bytes + producer gating) =============
  const int g = blockIdx.x & 3;   // group
  const int m = blockIdx.x >> 2;  // member 0..7
  const int tid = threadIdx.x;
  const int lane = tid & 63;
  const int w = tid >> 6;
  const int l15 = lane & 15;
  const int quad = lane >> 4;
  const int rowg0 = g << 4;

  // ---- B fragments, loaded once; keepalive in-loop forces residency ----
  h8_t bfrag[2][16];
  const int colbase = (m << 8) + (w << 5);
#pragma unroll
  for (int nt = 0; nt < 2; ++nt) {
#pragma unroll
    for (int kt = 0; kt < 16; ++kt) {
      int col = colbase + nt * 16 + l15;
      int k = kt * 32 + quad * 8;
      bfrag[nt][kt] = *(const h8_t*)&WHT[(size_t)col * 512 + k];
    }
  }

  const int r_ep = w;
  const int ug = (m << 6) + lane;
  // frag-layout dest uint indices for the two h stores (even lanes use them)
  const int ktu = ug >> 5, q3 = (ug >> 3) & 3, qi = (ug & 7) >> 1;
  const int d0 = ktu * 256 + (q3 * 16 + r_ep) * 4 + qi;
  const int d1 = ktu * 256 + (q3 * 16 + r_ep + 8) * 4 + qi;

  const unsigned long long* gp64 = (const unsigned long long*)GPh;

  float c0 = 0.f, c1 = 0.f;

  for (int t = 0; t < TT; ++t) {
    // ---- keepalive: mark bfrag as asm-redefined each iteration (rule-17) ----
#pragma unroll
    for (int nt = 0; nt < 2; ++nt)
#pragma unroll
      for (int kt = 0; kt < 16; ++kt)
        asm volatile("" : "+v"(bfrag[nt][kt]));

    const int tn = (t + 1 < TT) ? t + 1 : t;
    const int pG = t >> 1, pD = tn >> 1;

    // ---- single-wave combined poll: h flags (t>0) + producer counters ----
    if (w == 0) {
      const int* fb = flg + (g << 4);
      for (;;) {
        int ok = (__hip_atomic_load(&cnt[pG], __ATOMIC_RELAXED,
                                    __HIP_MEMORY_SCOPE_AGENT) >= 128) &
                 (__hip_atomic_load(&cnt[128 + pD], __ATOMIC_RELAXED,
                                    __HIP_MEMORY_SCOPE_AGENT) >= 32);
        if (t > 0)
          ok &= (__hip_atomic_load(&fb[lane & 7], __ATOMIC_RELAXED,
                                   __HIP_MEMORY_SCOPE_AGENT) >= t);
        if (__all(ok)) break;
        __builtin_amdgcn_s_sleep(1);
      }
    }
    __syncthreads();

    // ---- epilogue operand loads (agent atomics; data producer-published) ----
    const h4_t gha = __builtin_bit_cast(
        h4_t, __hip_atomic_load(
                  &gp64[((size_t)t * 64 + rowg0 + r_ep) * (NC / 4) + ug],
                  __ATOMIC_RELAXED, __HIP_MEMORY_SCOPE_AGENT));
    const h4_t ghb_ = __builtin_bit_cast(
        h4_t, __hip_atomic_load(
                  &gp64[((size_t)t * 64 + rowg0 + r_ep + 8) * (NC / 4) + ug],
                  __ATOMIC_RELAXED, __HIP_MEMORY_SCOPE_AGENT));
    const float dha =
        __hip_atomic_load(&DHf[((size_t)tn * 64 + rowg0 + r_ep) * HH + ug],
                          __ATOMIC_RELAXED, __HIP_MEMORY_SCOPE_AGENT);
    const float dhb =
        __hip_atomic_load(&DHf[((size_t)tn * 64 + rowg0 + r_ep + 8) * HH + ug],
                          __ATOMIC_RELAXED, __HIP_MEMORY_SCOPE_AGENT);

    // ---- stage the group's 16KB frag-linear slot into LDS (once/block) ----
    const unsigned long long* hsp =
        (const unsigned long long*)hs + ((size_t)(t & 1) * 4 + g) * 2048;
    unsigned long long sv0 = __hip_atomic_load(&hsp[tid], __ATOMIC_RELAXED,
                                               __HIP_MEMORY_SCOPE_AGENT);
    unsigned long long sv1 = __hip_atomic_load(&hsp[tid + 512], __ATOMIC_RELAXED,
                                               __HIP_MEMORY_SCOPE_AGENT);
    unsigned long long sv2 = __hip_atomic_load(&hsp[tid + 1024], __ATOMIC_RELAXED,
                                               __HIP_MEMORY_SCOPE_AGENT);
    unsigned long long sv3 = __hip_atomic_load(&hsp[tid + 1536], __ATOMIC_RELAXED,
                                               __HIP_MEMORY_SCOPE_AGENT);
    stag[tid] = sv0;
    stag[tid + 512] = sv1;
    stag[tid + 1024] = sv2;
    stag[tid + 1536] = sv3;
    __syncthreads();

    // ---- A fragments from LDS ----
    h8_t af[16];
#pragma unroll
    for (int kt = 0; kt < 16; ++kt) {
      ull2_t u2 = *(const ull2_t*)&stag[kt * 128 + lane * 2];
      af[kt] = __builtin_bit_cast(h8_t, u2);
    }

    // ---- MFMA ----
    f32x4 acc0 = {0.f, 0.f, 0.f, 0.f};
    f32x4 acc1 = {0.f, 0.f, 0.f, 0.f};
#pragma unroll
    for (int kt = 0; kt < 16; ++kt) {
      acc0 = __builtin_amdgcn_mfma_f32_16x16x32_f16(af[kt], bfrag[0][kt], acc0, 0, 0, 0);
      acc1 = __builtin_amdgcn_mfma_f32_16x16x32_f16(af[kt], bfrag[1][kt], acc1, 0, 0, 0);
    }
#pragma unroll
    for (int reg = 0; reg < 4; ++reg) {
      int row = quad * 4 + reg;
      gbuf[row * 260 + (w << 5) + l15] = acc0[reg];
      gbuf[row * 260 + (w << 5) + 16 + l15] = acc1[reg];
    }
    __syncthreads();

    // ---- epilogue: rows r_ep, r_ep+8 ; unit ug ----
    float h0v, h1v;
    {
      const float4 gv = *(const float4*)&gbuf[r_ep * 260 + (lane << 2)];
      float ig = sigmoidf_(gv.x + (float)gha[0]);
      float fg = sigmoidf_(gv.y + (float)gha[1]);
      float og = sigmoidf_(gv.z + (float)gha[2]);
      float ct = tanhf_(gv.w + (float)gha[3]);
      c0 = fg * c0 + ig * ct;
      h0v = og * tanhf_(c0);
    }
    {
      const float4 gv = *(const float4*)&gbuf[(r_ep + 8) * 260 + (lane << 2)];
      float ig = sigmoidf_(gv.x + (float)ghb_[0]);
      float fg = sigmoidf_(gv.y + (float)ghb_[1]);
      float og = sigmoidf_(gv.z + (float)ghb_[2]);
      float ct = tanhf_(gv.w + (float)ghb_[3]);
      c1 = fg * c1 + ig * ct;
      h1v = og * tanhf_(c1);
    }

    // ---- exchange + out stores BEFORE the drain (round-0 position) ----
    if (t + 1 < TT) {
      unsigned* hsn = hs + ((size_t)((t + 1) & 1) * 4 + g) * 4096;
      unsigned short hb0 = __half_as_ushort(__float2half(dha * h0v));
      unsigned o0 = (unsigned)__shfl_xor((int)(unsigned)hb0, 1) & 0xffffu;
      unsigned short hb1 = __half_as_ushort(__float2half(dhb * h1v));
      unsigned o1 = (unsigned)__shfl_xor((int)(unsigned)hb1, 1) & 0xffffu;
      if (!(lane & 1)) {
        __hip_atomic_store(&hsn[d0], (unsigned)hb0 | (o0 << 16), __ATOMIC_RELAXED,
                           __HIP_MEMORY_SCOPE_AGENT);
        __hip_atomic_store(&hsn[d1], (unsigned)hb1 | (o1 << 16), __ATOMIC_RELAXED,
                           __HIP_MEMORY_SCOPE_AGENT);
      }
    }
    out[((size_t)(rowg0 + r_ep) * TT + t) * HH + ug] = h0v;
    out[((size_t)(rowg0 + r_ep + 8) * TT + t) * HH + ug] = h1v;

    // ---- vm-drain barrier, then publish flag ----
    __syncthreads();  // compiler emits s_waitcnt vmcnt(0) per wave before barrier
    if (t + 1 < TT && tid == 0)
      __hip_atomic_store(&flg[(g << 4) + m], t + 1, __ATOMIC_RELAXED,
                         __HIP_MEMORY_SCOPE_AGENT);
  }
}

// ---------------------------------------------------------------------------
extern "C" void kernel_launch(void* const* d_in, const int* in_sizes, int n_in,
                              void* d_out, int out_size, void* d_ws,
                              size_t ws_size, hipStream_t stream) {
  const float* x = (const float*)d_in[0];
  const float* Xmean = (const float*)d_in[1];
  const float* Wi = (const float*)d_in[2];
  const float* bi = (const float*)d_in[3];
  const float* Wf = (const float*)d_in[4];
  const float* bf = (const float*)d_in[5];
  const float* Wo = (const float*)d_in[6];
  const float* bo = (const float*)d_in[7];
  const float* Wc = (const float*)d_in[8];
  const float* bc = (const float*)d_in[9];
  const float* gxw = (const float*)d_in[10];
  const float* gxb = (const float*)d_in[11];
  const float* ghW = (const float*)d_in[12];
  const float* ghb = (const float*)d_in[13];
  float* out = (float*)d_out;
  float* ws = (float*)d_ws;

  __half* AH = (__half*)(ws + AH_OFF);
  __half* DLh = (__half*)(ws + DLH_OFF);
  float* DH = ws + DH_OFF;
  __half* GPh = (__half*)(ws + GP_OFF);
  __half* WCT = (__half*)(ws + WCT_OFF);
  __half* GHT = (__half*)(ws + GHT_OFF);
  __half* WHT = (__half*)(ws + WHT_OFF);
  float* BC = ws + BC_OFF;
  unsigned* HS = (unsigned*)(ws + HS_OFF);
  int* FLG = (int*)(ws + FLG_OFF);

  // 1) prep: xt + repack + HS/FLG/CNT zeroing (independent parts, one launch)
  prep_kernel<<<9026, 256, 0, stream>>>(x, Xmean, gxw, gxb, AH, DLh,
                                        Wi, bi, Wf, bf, Wo, bo, Wc, bc, ghW,
                                        WCT, WHT, GHT, BC, HS);
  // 2) fused cooperative: 32 persist blocks + 224 gemm-producer blocks
  void* args[] = {(void*)&GPh, (void*)&DH,  (void*)&WHT, (void*)&HS,
                  (void*)&FLG, (void*)&out, (void*)&AH,  (void*)&WCT,
                  (void*)&BC,  (void*)&DLh, (void*)&GHT, (void*)&ghb};
  hipLaunchCooperativeKernel((const void*)fused_kernel, dim3(256), dim3(512),
                             args, 0, stream);
}

// Round 13
// 986.045 us; speedup vs baseline: 1.0444x; 1.0444x over previous
//
#include <hip/hip_runtime.h>
#include <hip/hip_fp16.h>
#include <math.h>

// Problem dims
#define TT 256
#define BB 64
#define DD 512
#define HH 512
#define NC 2048  // 4 gates * H, col = j*4+g (g: 0=i,1=f,2=o,3=ctilde)

// Workspace layout (float-slot offsets).
#define AH_OFF   0ull          // f16 [16384][1024]  (xt | m), row = t*64+b
#define DLH_OFF  8388608ull    // f16 [16384][512]   Dl
#define DH_OFF   12582912ull   // f32 [16384][512]   delta_h
#define GP_OFF   20971520ull   // f16 [16384][2048]  G_pre
#define WCT_OFF  37748736ull   // f16 [2048][1024]   gate W (x|m), col-major rows
#define GHT_OFF  38797312ull   // f16 [512][512]     gh_W transposed
#define WHT_OFF  38928384ull   // f16 [2048][512]    gate W h-part, col-major rows
#define BC_OFF   39452672ull   // f32 [2048]
#define HS_OFF   39454720ull   // uint [2][4 groups][4096] frag-linear h exchange
#define FLG_OFF  39487488ull   // int [4 groups][16] flags, 64B line per group

typedef _Float16 h8_t __attribute__((ext_vector_type(8)));
typedef _Float16 h4_t __attribute__((ext_vector_type(4)));
typedef float f32x4 __attribute__((ext_vector_type(4)));
typedef unsigned long long ull2_t __attribute__((ext_vector_type(2)));

typedef const __attribute__((address_space(1))) void* gas_p;
typedef __attribute__((address_space(3))) void* las_p;

__device__ __forceinline__ float fast_exp2(float x) {
#if defined(__has_builtin)
#if __has_builtin(__builtin_amdgcn_exp2f)
  return __builtin_amdgcn_exp2f(x);
#else
  return exp2f(x);
#endif
#else
  return exp2f(x);
#endif
}
__device__ __forceinline__ float fast_rcp(float x) {
#if defined(__has_builtin)
#if __has_builtin(__builtin_amdgcn_rcpf)
  return __builtin_amdgcn_rcpf(x);
#else
  return 1.0f / x;
#endif
#else
  return 1.0f / x;
#endif
}
#define LOG2E 1.4426950408889634f
__device__ __forceinline__ float sigmoidf_(float v) {
  return fast_rcp(1.0f + fast_exp2(-LOG2E * v));
}
__device__ __forceinline__ float tanhf_(float v) {
  return 1.0f - 2.0f * fast_rcp(1.0f + fast_exp2(2.0f * LOG2E * v));
}

// ---------------------------------------------------------------------------
// PREP kernel: xt (blocks 0..8191) + repack transpose (8192..9024) +
// HS/FLG zeroing (9025). xt first: it is the long pole, dispatch order
// starts it immediately; repack (short) and the zero block fill in behind.
// All three parts are mutually independent. Bodies identical to round-9/10
// proven kernels.
// ---------------------------------------------------------------------------
__global__ __launch_bounds__(256) void prep_kernel(
    const float* __restrict__ x, const float* __restrict__ Xmean,
    const float* __restrict__ gxw, const float* __restrict__ gxb,
    __half* __restrict__ AH, __half* __restrict__ DLh,
    const float* __restrict__ Wi, const float* __restrict__ bi,
    const float* __restrict__ Wf, const float* __restrict__ bff,
    const float* __restrict__ Wo, const float* __restrict__ bo,
    const float* __restrict__ Wc, const float* __restrict__ bc,
    const float* __restrict__ ghW,
    __half* __restrict__ WCT, __half* __restrict__ WHT,
    __half* __restrict__ GHT, float* __restrict__ BC,
    unsigned* __restrict__ HS) {
  const int bx = blockIdx.x;
  const int tid = threadIdx.x;

  if (bx < 8192) {
    // ---- xt: AH[r][d]=xt, AH[r][512+d]=m, DLh[r][d]=dl ; r=t*64+b ----
    int idx = bx * 256 + tid;
    int d = (idx & 127) * 4;
    int r = idx >> 7;
    int b = r & 63, t = r >> 6;
    size_t base = (((size_t)b * 4) * TT + t) * DD + d;
    const float4 X = *(const float4*)&x[base];
    const float4 Xl = *(const float4*)&x[base + (size_t)TT * DD];
    const float4 M = *(const float4*)&x[base + 2ull * TT * DD];
    const float4 Dl = *(const float4*)&x[base + 3ull * TT * DD];
    const float4 xm = *(const float4*)&Xmean[(size_t)t * DD + d];
    const float4 gw = *(const float4*)&gxw[d];
    const float4 gb = *(const float4*)&gxb[d];
    float o[4];
    {
      float dx = fast_exp2(-LOG2E * fmaxf(0.f, Dl.x * gw.x + gb.x));
      o[0] = M.x * X.x + (1.f - M.x) * (dx * Xl.x + (1.f - dx) * xm.x);
    }
    {
      float dx = fast_exp2(-LOG2E * fmaxf(0.f, Dl.y * gw.y + gb.y));
      o[1] = M.y * X.y + (1.f - M.y) * (dx * Xl.y + (1.f - dx) * xm.y);
    }
    {
      float dx = fast_exp2(-LOG2E * fmaxf(0.f, Dl.z * gw.z + gb.z));
      o[2] = M.z * X.z + (1.f - M.z) * (dx * Xl.z + (1.f - dx) * xm.z);
    }
    {
      float dx = fast_exp2(-LOG2E * fmaxf(0.f, Dl.w * gw.w + gb.w));
      o[3] = M.w * X.w + (1.f - M.w) * (dx * Xl.w + (1.f - dx) * xm.w);
    }
    h4_t xo = {(_Float16)o[0], (_Float16)o[1], (_Float16)o[2], (_Float16)o[3]};
    h4_t mo = {(_Float16)M.x, (_Float16)M.y, (_Float16)M.z, (_Float16)M.w};
    h4_t dlo = {(_Float16)Dl.x, (_Float16)Dl.y, (_Float16)Dl.z, (_Float16)Dl.w};
    *(h4_t*)&AH[(size_t)r * 1024 + d] = xo;
    *(h4_t*)&AH[(size_t)r * 1024 + 512 + d] = mo;
    *(h4_t*)&DLh[(size_t)r * 512 + d] = dlo;
    return;
  }

  if (bx == 9025) {  // zero HS (32768 uints) + FLG (64 ints, contiguous)
    for (int i = tid; i < 32832; i += 256) HS[i] = 0u;
    return;
  }

  const int rbx = bx - 8192;  // 0..832 repack
  if (rbx == 832) {           // bias block
    const float* bs[4] = {bi, bff, bo, bc};
    for (int j = tid; j < 512; j += 256)
#pragma unroll
      for (int g = 0; g < 4; ++g) BC[j * 4 + g] = bs[g][j];
    return;
  }
  __shared__ _Float16 tl[64][68];  // [jj][kk]; 136B rows: 8B-aligned, 2-way banks
  const int p = rbx % 13;          // panel
  const int tile = rbx / 13;       // 0..63
  const int k0 = (tile >> 3) << 6, j0 = (tile & 7) << 6;
  const float* Ws[4] = {Wi, Wf, Wo, Wc};

  const float* src;
  size_t koff;        // source row offset within W
  __half* dst;
  int dstride, dkoff, g = 0;
  if (p < 12) {
    g = p & 3;
    const int part = p >> 2;  // 0=x, 1=m, 2=h
    src = Ws[g];
    koff = (part == 0) ? 0 : (part == 1 ? 1024 : 512);
    if (part == 2) { dst = WHT; dstride = 512; dkoff = 0; }
    else           { dst = WCT; dstride = 1024; dkoff = (part == 1) ? 512 : 0; }
  } else {
    src = ghW; koff = 0; dst = GHT; dstride = 512; dkoff = 0;
  }

  // load 64x64 tile: lane -> jj (coalesced), 4 kk rows per pass
  const int jj = tid & 63, kr = tid >> 6;
#pragma unroll
  for (int r = 0; r < 16; ++r) {
    const int kk = r * 4 + kr;
    tl[jj][kk] = (_Float16)src[(koff + k0 + kk) * 512 + (j0 + jj)];
  }
  __syncthreads();

  // write transposed: thread -> (jj2, c4); h4 along k, 16 lanes = 128B run
  const int c4 = (tid & 15) * 4;
#pragma unroll
  for (int pass = 0; pass < 4; ++pass) {
    const int jj2 = (tid >> 4) + pass * 16;
    const h4_t v = *(const h4_t*)&tl[jj2][c4];
    size_t idx;
    if (p < 12)
      idx = (size_t)(4 * (j0 + jj2) + g) * dstride + dkoff + k0 + c4;
    else
      idx = (size_t)(j0 + jj2) * 512 + k0 + c4;
    *(h4_t*)&dst[idx] = v;
  }
}

// ---------------------------------------------------------------------------
// f16 MFMA GEMM body, m97 structure (proven rounds 1/4-11), 128x128 tile,
// 256 thr, K-step 32, linear LDS staged via global_load_lds width=16.
// XCD y-slice decode over the SUB-grid (id in [0,nblk), nblk multiple of 8;
// sub-grid bases are multiples of 8 so sub_id%8 == hardware XCD).
// mode 0: C f16. mode 1: C f32, exp(-relu(v)).
// ---------------------------------------------------------------------------
__device__ __forceinline__ void gemm_body(
    _Float16* Ash, _Float16* Bsh,
    const __half* __restrict__ A, const __half* __restrict__ BT,
    const float* __restrict__ bias, void* __restrict__ C,
    int K, int Ncols, int mode, int id, int nblk) {
  const int tid = threadIdx.x;
  const int lane = tid & 63, w = tid >> 6;
  const int l15 = lane & 15, quad = lane >> 4;
  const int wr = w >> 1, wc = w & 1;

  const int nx = Ncols >> 7;              // x-tiles
  const int ny = nblk / nx;               // y-tiles
  const int ysl = ny >> 3;                // y-tiles per XCD
  const int xcd = id & 7;
  const int q = id >> 3;
  const int row0 = (xcd * ysl + (q % ysl)) * 128;
  const int col0 = (q / ysl) * 128;

  f32x4 acc[4][4] = {};

  // staging chunk ci covers LDS bytes [ci*16, ci*16+16) == row ci>>2, halves (ci&3)*8
  const int ci0 = tid, ci1 = 256 + tid;
  const int ar0 = ci0 >> 2, ac0 = (ci0 & 3) * 8;
  const int ar1 = ci1 >> 2, ac1 = (ci1 & 3) * 8;
  const __half* Abase = A + (size_t)row0 * K;
  const __half* Bbase = BT + (size_t)col0 * K;

  for (int k0 = 0; k0 < K; k0 += 32) {
    __syncthreads();  // previous tile's readers done
    __builtin_amdgcn_global_load_lds((gas_p)(Abase + (size_t)ar0 * K + k0 + ac0),
                                     (las_p)(Ash + ci0 * 8), 16, 0, 0);
    __builtin_amdgcn_global_load_lds((gas_p)(Abase + (size_t)ar1 * K + k0 + ac1),
                                     (las_p)(Ash + ci1 * 8), 16, 0, 0);
    __builtin_amdgcn_global_load_lds((gas_p)(Bbase + (size_t)ar0 * K + k0 + ac0),
                                     (las_p)(Bsh + ci0 * 8), 16, 0, 0);
    __builtin_amdgcn_global_load_lds((gas_p)(Bbase + (size_t)ar1 * K + k0 + ac1),
                                     (las_p)(Bsh + ci1 * 8), 16, 0, 0);
    __syncthreads();  // vmcnt(0) drain -> tiles resident
    h8_t af[4], bf[4];
#pragma unroll
    for (int mt = 0; mt < 4; ++mt)
      af[mt] = *(const h8_t*)&Ash[(wr * 64 + mt * 16 + l15) * 32 + quad * 8];
#pragma unroll
    for (int ct = 0; ct < 4; ++ct)
      bf[ct] = *(const h8_t*)&Bsh[(wc * 64 + ct * 16 + l15) * 32 + quad * 8];
#pragma unroll
    for (int mt = 0; mt < 4; ++mt)
#pragma unroll
      for (int ct = 0; ct < 4; ++ct)
        acc[mt][ct] = __builtin_amdgcn_mfma_f32_16x16x32_f16(af[mt], bf[ct], acc[mt][ct], 0, 0, 0);
  }

#pragma unroll
  for (int ct = 0; ct < 4; ++ct) {
    const int col = col0 + wc * 64 + ct * 16 + l15;
    const float bv = bias[col];
#pragma unroll
    for (int mt = 0; mt < 4; ++mt) {
#pragma unroll
      for (int reg = 0; reg < 4; ++reg) {
        const int row = row0 + wr * 64 + mt * 16 + quad * 4 + reg;
        float v = acc[mt][ct][reg] + bv;
        if (mode == 0) {
          ((__half*)C)[(size_t)row * Ncols + col] = __float2half(v);
        } else {
          ((float*)C)[(size_t)row * Ncols + col] = fast_exp2(-LOG2E * fmaxf(0.f, v));
        }
      }
    }
  }
}

// GEMMS kernel: GP (blocks 0..2047, the long pole, dispatched first) + DH
// (2048..2559). Independent inputs/outputs; merging removes a launch gap and
// overlaps DH's short pass with GP's tail.
__global__ __launch_bounds__(256, 2) void gemms_kernel(
    const __half* __restrict__ AH, const __half* __restrict__ WCT,
    const float* __restrict__ BC, __half* __restrict__ GPh,
    const __half* __restrict__ DLh, const __half* __restrict__ GHT,
    const float* __restrict__ ghb, float* __restrict__ DHp) {
  __shared__ _Float16 Ash[128 * 32];
  __shared__ _Float16 Bsh[128 * 32];
  const int id = blockIdx.x;
  if (id < 2048) {
    // GP = [xt|m] @ [Wx;Wm] + BC : M=16384, N=2048, K=1024 (f16 out)
    gemm_body(Ash, Bsh, AH, WCT, BC, (void*)GPh, 1024, NC, 0, id, 2048);
  } else {
    // DH = exp(-relu(Dl @ ghW + ghb)) : M=16384, N=512, K=512 (f32 out)
    gemm_body(Ash, Bsh, DLh, GHT, ghb, (void*)DHp, 512, 512, 1, id - 2048, 512);
  }
}

// ---------------------------------------------------------------------------
// Recurrence: 32 blocks x 512 threads, cooperative. 4 groups of 8 blocks.
// Group g owns rows [16g,16g+16); member m owns gate cols [256m,256m+256).
// FROZEN at the round-6 bytes (hardware-proven 639-643us persist).
// ---------------------------------------------------------------------------
__global__ __launch_bounds__(512)
__attribute__((amdgpu_waves_per_eu(2, 2))) void persist_rnn(
    const __half* __restrict__ GPh, const float* __restrict__ DH,
    const __half* __restrict__ WHT, unsigned* __restrict__ hs,
    int* __restrict__ flg, float* __restrict__ out) {
  __shared__ __align__(16) float gbuf[16 * 260];
  __shared__ __align__(16) unsigned long long stag[2048];  // 16KB A-slot mirror
  const int g = blockIdx.x & 3;   // group
  const int m = blockIdx.x >> 2;  // member 0..7
  const int tid = threadIdx.x;
  const int lane = tid & 63;
  const int w = tid >> 6;
  const int l15 = lane & 15;
  const int quad = lane >> 4;
  const int rowg0 = g << 4;

  // ---- B fragments, loaded once; keepalive in-loop forces residency ----
  h8_t bfrag[2][16];
  const int colbase = (m << 8) + (w << 5);
#pragma unroll
  for (int nt = 0; nt < 2; ++nt) {
#pragma unroll
    for (int kt = 0; kt < 16; ++kt) {
      int col = colbase + nt * 16 + l15;
      int k = kt * 32 + quad * 8;
      bfrag[nt][kt] = *(const h8_t*)&WHT[(size_t)col * 512 + k];
    }
  }

  const int r_ep = w;
  const int ug = (m << 6) + lane;
  // frag-layout dest uint indices for the two h stores (even lanes use them)
  const int ktu = ug >> 5, q3 = (ug >> 3) & 3, qi = (ug & 7) >> 1;
  const int d0 = ktu * 256 + (q3 * 16 + r_ep) * 4 + qi;
  const int d1 = ktu * 256 + (q3 * 16 + r_ep + 8) * 4 + qi;

  float c0 = 0.f, c1 = 0.f;

  for (int t = 0; t < TT; ++t) {
    // ---- keepalive: mark bfrag as asm-redefined each iteration (rule-17) ----
#pragma unroll
    for (int nt = 0; nt < 2; ++nt)
#pragma unroll
      for (int kt = 0; kt < 16; ++kt)
        asm volatile("" : "+v"(bfrag[nt][kt]));

    // ---- epilogue operand loads for THIS step: in flight across poll+stage
    const h4_t gha = *(const h4_t*)&GPh[((size_t)t * 64 + rowg0 + r_ep) * NC + (ug << 2)];
    const h4_t ghb = *(const h4_t*)&GPh[((size_t)t * 64 + rowg0 + r_ep + 8) * NC + (ug << 2)];
    const int tn = (t + 1 < TT) ? t + 1 : t;
    const float dha = DH[((size_t)tn * 64 + rowg0 + r_ep) * HH + ug];
    const float dhb = DH[((size_t)tn * 64 + rowg0 + r_ep + 8) * HH + ug];

    // ---- single-wave poll, barrier release ----
    if (t > 0) {
      if (w == 0) {
        const int* fb = flg + (g << 4);
        for (;;) {
          int v = __hip_atomic_load(&fb[lane & 7], __ATOMIC_RELAXED,
                                    __HIP_MEMORY_SCOPE_AGENT);
          if (__all(v >= t)) break;
          __builtin_amdgcn_s_sleep(1);
        }
      }
      __syncthreads();
    }

    // ---- stage the group's 16KB frag-linear slot into LDS (once/block) ----
    const unsigned long long* hsp =
        (const unsigned long long*)hs + ((size_t)(t & 1) * 4 + g) * 2048;
    unsigned long long sv0 = __hip_atomic_load(&hsp[tid], __ATOMIC_RELAXED,
                                               __HIP_MEMORY_SCOPE_AGENT);
    unsigned long long sv1 = __hip_atomic_load(&hsp[tid + 512], __ATOMIC_RELAXED,
                                               __HIP_MEMORY_SCOPE_AGENT);
    unsigned long long sv2 = __hip_atomic_load(&hsp[tid + 1024], __ATOMIC_RELAXED,
                                               __HIP_MEMORY_SCOPE_AGENT);
    unsigned long long sv3 = __hip_atomic_load(&hsp[tid + 1536], __ATOMIC_RELAXED,
                                               __HIP_MEMORY_SCOPE_AGENT);
    stag[tid] = sv0;
    stag[tid + 512] = sv1;
    stag[tid + 1024] = sv2;
    stag[tid + 1536] = sv3;
    __syncthreads();

    // ---- A fragments from LDS ----
    h8_t af[16];
#pragma unroll
    for (int kt = 0; kt < 16; ++kt) {
      ull2_t u2 = *(const ull2_t*)&stag[kt * 128 + lane * 2];
      af[kt] = __builtin_bit_cast(h8_t, u2);
    }

    // ---- MFMA ----
    f32x4 acc0 = {0.f, 0.f, 0.f, 0.f};
    f32x4 acc1 = {0.f, 0.f, 0.f, 0.f};
#pragma unroll
    for (int kt = 0; kt < 16; ++kt) {
      acc0 = __builtin_amdgcn_mfma_f32_16x16x32_f16(af[kt], bfrag[0][kt], acc0, 0, 0, 0);
      acc1 = __builtin_amdgcn_mfma_f32_16x16x32_f16(af[kt], bfrag[1][kt], acc1, 0, 0, 0);
    }
#pragma unroll
    for (int reg = 0; reg < 4; ++reg) {
      int row = quad * 4 + reg;
      gbuf[row * 260 + (w << 5) + l15] = acc0[reg];
      gbuf[row * 260 + (w << 5) + 16 + l15] = acc1[reg];
    }
    __syncthreads();

    // ---- epilogue: rows r_ep, r_ep+8 ; unit ug ----
    float h0v, h1v;
    {
      const float4 gv = *(const float4*)&gbuf[r_ep * 260 + (lane << 2)];
      float ig = sigmoidf_(gv.x + (float)gha[0]);
      float fg = sigmoidf_(gv.y + (float)gha[1]);
      float og = sigmoidf_(gv.z + (float)gha[2]);
      float ct = tanhf_(gv.w + (float)gha[3]);
      c0 = fg * c0 + ig * ct;
      h0v = og * tanhf_(c0);
    }
    {
      const float4 gv = *(const float4*)&gbuf[(r_ep + 8) * 260 + (lane << 2)];
      float ig = sigmoidf_(gv.x + (float)ghb[0]);
      float fg = sigmoidf_(gv.y + (float)ghb[1]);
      float og = sigmoidf_(gv.z + (float)ghb[2]);
      float ct = tanhf_(gv.w + (float)ghb[3]);
      c1 = fg * c1 + ig * ct;
      h1v = og * tanhf_(c1);
    }

    // ---- exchange + out stores BEFORE the drain (round-0 position) ----
    if (t + 1 < TT) {
      unsigned* hsn = hs + ((size_t)((t + 1) & 1) * 4 + g) * 4096;
      unsigned short hb0 = __half_as_ushort(__float2half(dha * h0v));
      unsigned o0 = (unsigned)__shfl_xor((int)(unsigned)hb0, 1) & 0xffffu;
      unsigned short hb1 = __half_as_ushort(__float2half(dhb * h1v));
      unsigned o1 = (unsigned)__shfl_xor((int)(unsigned)hb1, 1) & 0xffffu;
      if (!(lane & 1)) {
        __hip_atomic_store(&hsn[d0], (unsigned)hb0 | (o0 << 16), __ATOMIC_RELAXED,
                           __HIP_MEMORY_SCOPE_AGENT);
        __hip_atomic_store(&hsn[d1], (unsigned)hb1 | (o1 << 16), __ATOMIC_RELAXED,
                           __HIP_MEMORY_SCOPE_AGENT);
      }
    }
    out[((size_t)(rowg0 + r_ep) * TT + t) * HH + ug] = h0v;
    out[((size_t)(rowg0 + r_ep + 8) * TT + t) * HH + ug] = h1v;

    // ---- vm-drain barrier, then publish flag ----
    __syncthreads();  // compiler emits s_waitcnt vmcnt(0) per wave before barrier
    if (t + 1 < TT && tid == 0)
      __hip_atomic_store(&flg[(g << 4) + m], t + 1, __ATOMIC_RELAXED,
                         __HIP_MEMORY_SCOPE_AGENT);
  }
}

// ---------------------------------------------------------------------------
extern "C" void kernel_launch(void* const* d_in, const int* in_sizes, int n_in,
                              void* d_out, int out_size, void* d_ws,
                              size_t ws_size, hipStream_t stream) {
  const float* x = (const float*)d_in[0];
  const float* Xmean = (const float*)d_in[1];
  const float* Wi = (const float*)d_in[2];
  const float* bi = (const float*)d_in[3];
  const float* Wf = (const float*)d_in[4];
  const float* bf = (const float*)d_in[5];
  const float* Wo = (const float*)d_in[6];
  const float* bo = (const float*)d_in[7];
  const float* Wc = (const float*)d_in[8];
  const float* bc = (const float*)d_in[9];
  const float* gxw = (const float*)d_in[10];
  const float* gxb = (const float*)d_in[11];
  const float* ghW = (const float*)d_in[12];
  const float* ghb = (const float*)d_in[13];
  float* out = (float*)d_out;
  float* ws = (float*)d_ws;

  __half* AH = (__half*)(ws + AH_OFF);
  __half* DLh = (__half*)(ws + DLH_OFF);
  float* DH = ws + DH_OFF;
  __half* GPh = (__half*)(ws + GP_OFF);
  __half* WCT = (__half*)(ws + WCT_OFF);
  __half* GHT = (__half*)(ws + GHT_OFF);
  __half* WHT = (__half*)(ws + WHT_OFF);
  float* BC = ws + BC_OFF;
  unsigned* HS = (unsigned*)(ws + HS_OFF);
  int* FLG = (int*)(ws + FLG_OFF);

  // 1) prep: xt + repack + HS/FLG zeroing (independent parts, one launch)
  prep_kernel<<<9026, 256, 0, stream>>>(x, Xmean, gxw, gxb, AH, DLh,
                                        Wi, bi, Wf, bf, Wo, bo, Wc, bc, ghW,
                                        WCT, WHT, GHT, BC, HS);
  // 2) gemms: GP (2048 blocks) + DH (512 blocks), concurrent
  gemms_kernel<<<2560, 256, 0, stream>>>(AH, WCT, BC, GPh, DLh, GHT, ghb, DH);
  // 3) recurrence
  void* args[] = {(void*)&GPh, (void*)&DH, (void*)&WHT,
                  (void*)&HS, (void*)&FLG, (void*)&out};
  hipLaunchCooperativeKernel((const void*)persist_rnn, dim3(32), dim3(512),
                             args, 0, stream);
}